// Round 10
// baseline (153.700 us; speedup 1.0000x reference)
//
#include <hip/hip_runtime.h>
#include <math.h>

// ---------------------------------------------------------------------------
// GraphMultisetTransformer forward, MI355X round 10:
//   - CHUNK=32, LDS 32KB, launch_bounds(512,8) -> 4 blocks/CU (100% occ target)
//   - S = X @ Wqk^T fusion (K never materialized), single-group chunks
//   - Po stored bf16 via LDS o-transpose + uint4 stores (write amplification fix)
//   - grid=512 balanced persistent blocks, XCD-chunked ranges
// ---------------------------------------------------------------------------

typedef __bf16 bf16x8 __attribute__((ext_vector_type(8)));
typedef float  f32x4  __attribute__((ext_vector_type(4)));

namespace {
constexpr int kB   = 16;
constexpr int kN   = 4096;
constexpr int kC   = 256;
constexpr int kEV  = 64;
constexpr int kH   = 8;
constexpr int kDH  = 32;
constexpr int kNQ  = 30;
constexpr int kCH  = 32;            // chunk rows
constexpr int kMaxT = 2064;         // 16*3*ceil(1365/32) cap for Pl/Po sizing
constexpr int kGrid = 512;          // chunk grid
constexpr float kScale = 0.625f;    // 1/(16*0.1)
}

__device__ __forceinline__ unsigned short f32_to_bf16(float f) {
  unsigned int u = __float_as_uint(f);
  unsigned int r = (u + 0x7FFFu + ((u >> 16) & 1u)) >> 16;
  return (unsigned short)r;
}
__device__ __forceinline__ unsigned int pack_bf16(float a, float b) {
  return (unsigned int)f32_to_bf16(a) | ((unsigned int)f32_to_bf16(b) << 16);
}
__device__ __forceinline__ float bf16_to_f32(unsigned short u) {
  return __uint_as_float((unsigned int)u << 16);
}
__device__ __forceinline__ f32x4 splat4(float v) {
  f32x4 r; r[0] = v; r[1] = v; r[2] = v; r[3] = v; return r;
}
// 2-way-free swizzle for [32][256]bf16 tiles read as row-lane A-frags
__device__ __forceinline__ int swz_f(int row) {
  return ((row & 7) << 2) | (((row >> 3) & 1) << 1);
}

// ---------------------------------------------------------------------------
// prep: [0,96) Wv f32->bf16 | [96,144) Wk -> bf16 transposed (WkT) |
//       [144,656) Q proj -> Qw f32 + Qb bf16*scale | [656,1040) wd partials
// ---------------------------------------------------------------------------
__global__ __launch_bounds__(256) void prep_kernel(
    const float* __restrict__ ev,
    const float* __restrict__ WqG, const float* __restrict__ WqD,
    const float* __restrict__ WqL,
    const float* __restrict__ WkG, const float* __restrict__ WkD,
    const float* __restrict__ WkL,
    const float* __restrict__ WvG, const float* __restrict__ WvD,
    const float* __restrict__ WvL,
    unsigned short* __restrict__ Wb,     // 3 x Wv bf16
    unsigned short* __restrict__ WkT,    // 3 x Wk^T bf16
    float* __restrict__ Qw, unsigned short* __restrict__ Qb,
    float* __restrict__ wdp)
{
  const int bid = blockIdx.x, tid = threadIdx.x;

  if (bid < 96) {                       // ---- Wv convert ----
    const int mat = bid >> 5;
    const float* src = (mat == 0) ? WvG : (mat == 1) ? WvD : WvL;
    const int i0 = (((bid & 31) << 8) + tid) * 8;
    const float4* s4 = (const float4*)(src + i0);
    float4 a = s4[0], b = s4[1];
    uint4 pack = make_uint4(pack_bf16(a.x, a.y), pack_bf16(a.z, a.w),
                            pack_bf16(b.x, b.y), pack_bf16(b.z, b.w));
    *(uint4*)(Wb + (size_t)mat * 65536 + i0) = pack;
    return;
  }

  if (bid < 144) {                      // ---- Wk transpose -> bf16 ----
    __shared__ float ts[64][65];
    const int t2 = bid - 96;
    const int mat = t2 >> 4, tile = t2 & 15;
    const int r0 = (tile >> 2) * 64, c0 = (tile & 3) * 64;
    const float* src = (mat == 0) ? WkG : (mat == 1) ? WkD : WkL;
#pragma unroll
    for (int it = 0; it < 16; ++it) {
      const int idx = tid + it * 256;
      const int r = idx >> 6, c = idx & 63;
      ts[r][c] = src[(size_t)(r0 + r) * kC + c0 + c];
    }
    __syncthreads();
#pragma unroll
    for (int it = 0; it < 16; ++it) {
      const int idx = tid + it * 256;
      const int r = idx >> 6, c = idx & 63;
      WkT[(size_t)mat * 65536 + (size_t)(c0 + r) * kC + r0 + c] =
          f32_to_bf16(ts[c][r]);
    }
    return;
  }

  if (bid < 656) {                      // ---- Q projection ----
    __shared__ float e[kEV];
    const int idx = bid - 144;
    const int b = idx >> 5, qq = idx & 31;
    if (qq >= kNQ) { Qb[((size_t)(b * 32 + qq)) * kC + tid] = 0; return; }
    if (tid < kEV) e[tid] = ev[((size_t)(b * kNQ + qq)) * kEV + tid];
    __syncthreads();
    const float* W = (qq < 10) ? WqG : (qq < 20) ? WqD : WqL;
    const float4* wr = (const float4*)(W + (size_t)tid * kEV);
    const float4* er = (const float4*)e;
    float s = 0.0f;
#pragma unroll
    for (int j = 0; j < kEV / 4; ++j) {
      float4 w = wr[j], v = er[j];
      s = fmaf(v.x, w.x, s); s = fmaf(v.y, w.y, s);
      s = fmaf(v.z, w.z, s); s = fmaf(v.w, w.w, s);
    }
    Qw[((size_t)(b * kNQ + qq)) * kC + tid] = s;
    Qb[((size_t)(b * 32 + qq)) * kC + tid] = f32_to_bf16(s * kScale);
    return;
  }

  // ---- wd partials: one block per (b,g,h), inline Q from ev ----
  {
    __shared__ float evs[10][64];
    __shared__ float Qblk[10][33];
    __shared__ float sred[256];
    const int w = bid - 656;            // [0,384)
    const int b = w / 24, r = w % 24, g = r >> 3, h = r & 7;
    const int lo = g * 10;
    const float* Wqg = (g == 0) ? WqG : (g == 1) ? WqD : WqL;
    for (int i = tid; i < 640; i += 256) {
      const int q = i >> 6, e2 = i & 63;
      evs[q][e2] = ev[((size_t)(b * kNQ + lo + q)) * kEV + e2];
    }
    __syncthreads();
    for (int i = tid; i < 320; i += 256) {
      const int q = i >> 5, kk = i & 31;
      const float* wp = Wqg + (size_t)(h * 32 + kk) * kEV;
      float s = 0.0f;
#pragma unroll
      for (int e4 = 0; e4 < 16; ++e4) {
        float4 ev4 = *(const float4*)&evs[q][e4 * 4];
        float4 w4  = *(const float4*)(wp + e4 * 4);
        s = fmaf(ev4.x, w4.x, s); s = fmaf(ev4.y, w4.y, s);
        s = fmaf(ev4.z, w4.z, s); s = fmaf(ev4.w, w4.w, s);
      }
      Qblk[q][kk] = s;
    }
    __syncthreads();
    float v = 0.0f;
    if (tid < 100) {
      const int i = tid / 10, j = tid % 10;
      float corr = 0.0f;
#pragma unroll
      for (int k = 0; k < kDH; ++k) corr = fmaf(Qblk[i][k], Qblk[j][k], corr);
      const float diff = corr - (i == j ? 1.0f : 0.0f);
      v = diff * diff;
    }
    sred[tid] = v;
    __syncthreads();
    for (int s2 = 128; s2 > 0; s2 >>= 1) {
      if (tid < s2) sred[tid] += sred[tid + s2];
      __syncthreads();
    }
    if (tid == 0) wdp[w] = sqrtf(sred[0]) * (1.0f / 16.0f);
  }
}

// ---------------------------------------------------------------------------
// wqk: Wqk[b,g,h][q 32][k 256] = Qb[b][q][h*32..+32] @ WkT_g[k][h*32..+32]
// grid 48 = (b,g), 512 thr (wave = head). 32 MFMA/wave.
// ---------------------------------------------------------------------------
__global__ __launch_bounds__(512) void wqk_kernel(
    const unsigned short* __restrict__ Qb,
    const unsigned short* __restrict__ WkT,
    unsigned short* __restrict__ Wqkb)
{
  const int bid = blockIdx.x, tid = threadIdx.x;
  const int b = bid / 3, g = bid % 3;
  const int lane = tid & 63, h = tid >> 6;
  const int lg = lane >> 4, lr = lane & 15;

  const unsigned short* WkT_g = WkT + (size_t)g * 65536;

  bf16x8 aq[2];
#pragma unroll
  for (int mt = 0; mt < 2; ++mt)
    aq[mt] = *reinterpret_cast<const bf16x8*>(
        Qb + (size_t)(b * 32 + mt * 16 + lr) * kC + h * 32 + lg * 8);

  f32x4 acc[2][16];
#pragma unroll
  for (int mt = 0; mt < 2; ++mt)
#pragma unroll
    for (int nt = 0; nt < 16; ++nt) acc[mt][nt] = splat4(0.0f);

#pragma unroll
  for (int nt = 0; nt < 16; ++nt) {
    bf16x8 bw = *reinterpret_cast<const bf16x8*>(
        WkT_g + (size_t)(nt * 16 + lr) * kC + h * 32 + lg * 8);
    acc[0][nt] = __builtin_amdgcn_mfma_f32_16x16x32_bf16(aq[0], bw, acc[0][nt], 0, 0, 0);
    acc[1][nt] = __builtin_amdgcn_mfma_f32_16x16x32_bf16(aq[1], bw, acc[1][nt], 0, 0, 0);
  }

  unsigned short* dst = Wqkb + ((size_t)((b * 3 + g) * 8 + h)) * 32 * kC;
#pragma unroll
  for (int mt = 0; mt < 2; ++mt)
#pragma unroll
    for (int nt = 0; nt < 16; ++nt)
#pragma unroll
      for (int j = 0; j < 4; ++j) {
        const int q = mt * 16 + lg * 4 + j;
        dst[(size_t)q * kC + nt * 16 + lr] = f32_to_bf16(acc[mt][nt][j]);
      }
}

// ---------------------------------------------------------------------------
// Chunk kernel: grid = 512, 512 thr, 32KB LDS -> 4 blocks/CU (8 waves/SIMD).
// 32-row chunks; per chunk: stage -> B1 -> S-proj/exp -> V-proj -> B2 ->
// P/Vt -> PV -> o via LDS transpose -> bf16 Po stores -> B3.
// ---------------------------------------------------------------------------
__global__ __launch_bounds__(512, 8) void chunk_kernel(
    const float* __restrict__ x, const float* __restrict__ ox,
    const int* __restrict__ numv,
    const unsigned short* __restrict__ Wb,      // 3 Wv matrices bf16
    const float* __restrict__ bvG, const float* __restrict__ bvD,
    const float* __restrict__ bvL,
    const unsigned short* __restrict__ Wqkb,    // [b,g,h][32][256] bf16
    float* __restrict__ Pl, unsigned short* __restrict__ Po)
{
  __shared__ unsigned short Xs[kCH * kC];   // 16KB: x staging -> P/o (8x2KB)
  __shared__ unsigned short Ov[kCH * kC];   // 16KB: ox staging -> Vt (8x2KB)

  const int tid = threadIdx.x;
  const int lane = tid & 63, wv = tid >> 6;
  const int lg = lane >> 4, lr = lane & 15;
  const int wcol0 = wv * 32;
  const int h = wv;                                  // wave = head

  int nv[17];
#pragma unroll
  for (int i = 0; i < 17; ++i) nv[i] = numv[i];
  int Tall = 0;
#pragma unroll
  for (int bb = 0; bb < kB; ++bb)
    Tall += 3 * ((nv[bb + 1] - nv[bb] + kCH - 1) / kCH);

  const int vp = (blockIdx.x & 7) * (kGrid / 8) + (blockIdx.x >> 3);
  const int lo = (vp * Tall) / kGrid;
  const int hi = ((vp + 1) * Tall) / kGrid;

  for (int tt = lo; tt < hi; ++tt) {
    // ---- decode (b, g, ch) ----
    int rem = tt, b = -1, g = 0, ch = 0;
#pragma unroll
    for (int bb = 0; bb < kB; ++bb) {
      const int cb = (nv[bb + 1] - nv[bb] + kCH - 1) / kCH;
#pragma unroll
      for (int gg = 0; gg < 3; ++gg) {
        if (b < 0) { if (rem < cb) { b = bb; g = gg; ch = rem; } else rem -= cb; }
      }
    }

    const int d = nv[b + 1] - nv[b];
    const int row0 = g * d + ch * kCH;
    const int nvalid = min(kCH, d - ch * kCH);

    const unsigned short* Wv_g = Wb + (size_t)g * 65536;
    const float* bv = (g == 0) ? bvG : (g == 1) ? bvD : bvL;
    const unsigned short* Wqk_h =
        Wqkb + ((size_t)((b * 3 + g) * 8 + h)) * 32 * kC;

    // ---- staging: all x/ox loads issued up front (2 slots x 32B each) ----
    {
      const float* xb = x + (size_t)b * kN * kC;
      const float* ob = ox + (size_t)b * kN * kC;
      float4 xa[4], oa[4];
      int off[2];
#pragma unroll
      for (int i = 0; i < 2; ++i) {
        const int sid = tid + i * 512;               // [0,1024) 32B slots
        const int row = sid >> 5, c5 = sid & 31;
        const int rg = min(row0 + row, kN - 1);
        off[i] = rg * kC + c5 * 8;
        const float4* sx = (const float4*)(xb + off[i]);
        xa[2 * i] = sx[0]; xa[2 * i + 1] = sx[1];
      }
#pragma unroll
      for (int i = 0; i < 2; ++i) {
        const float4* so = (const float4*)(ob + off[i]);
        oa[2 * i] = so[0]; oa[2 * i + 1] = so[1];
      }
#pragma unroll
      for (int i = 0; i < 2; ++i) {
        const int sid = tid + i * 512;
        const int row = sid >> 5, c5 = sid & 31;
        const int base = row * kC + ((c5 ^ swz_f(row)) * 8);
        *(uint4*)(Xs + base) = make_uint4(
            pack_bf16(xa[2 * i].x, xa[2 * i].y), pack_bf16(xa[2 * i].z, xa[2 * i].w),
            pack_bf16(xa[2 * i + 1].x, xa[2 * i + 1].y),
            pack_bf16(xa[2 * i + 1].z, xa[2 * i + 1].w));
        *(uint4*)(Ov + base) = make_uint4(
            pack_bf16(oa[2 * i].x, oa[2 * i].y), pack_bf16(oa[2 * i].z, oa[2 * i].w),
            pack_bf16(oa[2 * i + 1].x, oa[2 * i + 1].y),
            pack_bf16(oa[2 * i + 1].z, oa[2 * i + 1].w));
      }
    }
    __syncthreads();                                 // B1: tiles staged

    // ---- S-projection: S[key 32][q 32] = X @ Wqk_h^T ----
    f32x4 s[2][2];
#pragma unroll
    for (int m = 0; m < 2; ++m)
#pragma unroll
      for (int n = 0; n < 2; ++n) s[m][n] = splat4(0.0f);

#pragma unroll
    for (int kt = 0; kt < 8; ++kt) {
      bf16x8 a[2];
#pragma unroll
      for (int m = 0; m < 2; ++m) {
        const int row = m * 16 + lr;
        const int c16 = (kt * 4 + lg) ^ swz_f(row);
        a[m] = *reinterpret_cast<const bf16x8*>(Xs + row * kC + c16 * 8);
      }
      const int k0 = kt * 32 + lg * 8;
#pragma unroll
      for (int n = 0; n < 2; ++n) {
        bf16x8 bq = *reinterpret_cast<const bf16x8*>(
            Wqk_h + (size_t)(n * 16 + lr) * kC + k0);
#pragma unroll
        for (int m = 0; m < 2; ++m)
          s[m][n] = __builtin_amdgcn_mfma_f32_16x16x32_bf16(a[m], bq, s[m][n], 0, 0, 0);
      }
    }

    // ---- exp -> packed bf16 P in regs; row-sums ----
    unsigned int pp[2][2][2];
    f32x4 lsum[2];
    lsum[0] = splat4(0.0f); lsum[1] = splat4(0.0f);
#pragma unroll
    for (int m = 0; m < 2; ++m)
#pragma unroll
      for (int n = 0; n < 2; ++n) {
        f32x4 pv;
#pragma unroll
        for (int j = 0; j < 4; ++j) {
          const int key = m * 16 + lg * 4 + j;
          pv[j] = (key < nvalid) ? __expf(s[m][n][j]) : 0.0f;
        }
        lsum[n] += pv;
        pp[m][n][0] = pack_bf16(pv[0], pv[1]);
        pp[m][n][1] = pack_bf16(pv[2], pv[3]);
      }
    float ls[2];
#pragma unroll
    for (int n = 0; n < 2; ++n) {
      float v = (lsum[n][0] + lsum[n][1]) + (lsum[n][2] + lsum[n][3]);
      v += __shfl_xor(v, 16);
      v += __shfl_xor(v, 32);
      ls[n] = v;
    }
    if (lg == 0) {
#pragma unroll
      for (int n = 0; n < 2; ++n) {
        const int q = n * 16 + lr;
        if (q < kNQ) Pl[((size_t)tt * kNQ + q) * kH + h] = ls[n];
      }
    }

    // ---- V projection (acc in regs across B2) ----
    f32x4 vacc[2][2];
#pragma unroll
    for (int n = 0; n < 2; ++n) {
      const float bvv = bv[wcol0 + n * 16 + lr];
#pragma unroll
      for (int m = 0; m < 2; ++m) vacc[m][n] = splat4(bvv);
    }
#pragma unroll
    for (int kt = 0; kt < 8; ++kt) {
      bf16x8 a[2];
#pragma unroll
      for (int m = 0; m < 2; ++m) {
        const int row = m * 16 + lr;
        const int c16 = (kt * 4 + lg) ^ swz_f(row);
        a[m] = *reinterpret_cast<const bf16x8*>(Ov + row * kC + c16 * 8);
      }
      const int k0 = kt * 32 + lg * 8;
#pragma unroll
      for (int n = 0; n < 2; ++n) {
        bf16x8 bw = *reinterpret_cast<const bf16x8*>(
            Wv_g + (size_t)(wcol0 + n * 16 + lr) * kC + k0);
#pragma unroll
        for (int m = 0; m < 2; ++m)
          vacc[m][n] = __builtin_amdgcn_mfma_f32_16x16x32_bf16(a[m], bw, vacc[m][n], 0, 0, 0);
      }
    }
    __syncthreads();               // B2: all Xs/Ov reads done; safe to overwrite

    // ---- P -> own-wave Xs slot [32 q][32 key] (2KB), chunk swz ^(q&3) ----
    unsigned short* Pw = Xs + wv * 1024;
#pragma unroll
    for (int m = 0; m < 2; ++m)
#pragma unroll
      for (int n = 0; n < 2; ++n) {
        const int q = n * 16 + lr;
        const int ck = (2 * m + (lg >> 1)) ^ (q & 3);
        unsigned short* pa = Pw + q * kCH + ck * 8 + (lg & 1) * 4;
        *(unsigned int*)(pa) = pp[m][n][0];
        *(unsigned int*)(pa + 2) = pp[m][n][1];
      }

    // ---- Vt -> own-wave Ov slot [32 col][32 key] (2KB), swz ^(col&3) ----
    unsigned short* Vw = Ov + wv * 1024;
#pragma unroll
    for (int m = 0; m < 2; ++m)
#pragma unroll
      for (int n = 0; n < 2; ++n) {
        const int cl = n * 16 + lr;                  // local col
        const int k0r = m * 16 + lg * 4;
        const int ck = (2 * m + (lg >> 1)) ^ (cl & 3);
        *(unsigned int*)(Vw + cl * kCH + ck * 8 + (lg & 1) * 4) =
            pack_bf16(vacc[m][n][0], vacc[m][n][1]);
        *(unsigned int*)(Vw + cl * kCH + ck * 8 + (lg & 1) * 4 + 2) =
            pack_bf16(vacc[m][n][2], vacc[m][n][3]);
        (void)k0r;
      }

    // ---- PV: O[q][dh] = sum_key P[q][key] * V[key][dh]  (same-wave LDS) ----
    f32x4 o[2][2];
#pragma unroll
    for (int m = 0; m < 2; ++m)
#pragma unroll
      for (int n = 0; n < 2; ++n) o[m][n] = splat4(0.0f);

    {
      bf16x8 ap[2];
#pragma unroll
      for (int mq = 0; mq < 2; ++mq) {
        const int q = mq * 16 + lr;
        ap[mq] = *reinterpret_cast<const bf16x8*>(
            Pw + q * kCH + ((lg ^ (q & 3))) * 8);
      }
#pragma unroll
      for (int n = 0; n < 2; ++n) {
        const int cl = n * 16 + lr;
        bf16x8 bvf = *reinterpret_cast<const bf16x8*>(
            Vw + cl * kCH + ((lg ^ (cl & 3))) * 8);
        o[0][n] = __builtin_amdgcn_mfma_f32_16x16x32_bf16(ap[0], bvf, o[0][n], 0, 0, 0);
        o[1][n] = __builtin_amdgcn_mfma_f32_16x16x32_bf16(ap[1], bvf, o[1][n], 0, 0, 0);
      }
    }

    // ---- o -> LDS (P slot, dead) as [32 q][32 dh] bf16, then uint4 stores --
#pragma unroll
    for (int mq = 0; mq < 2; ++mq)
#pragma unroll
      for (int n = 0; n < 2; ++n)
#pragma unroll
        for (int j = 0; j < 4; ++j) {
          const int q = mq * 16 + lg * 4 + j;
          Pw[q * kDH + n * 16 + lr] = f32_to_bf16(o[mq][n][j]);
        }
    // wave-private: DS ops in order, no barrier needed
    {
      unsigned short* pdst = Po + (((size_t)tt * kNQ) * kH + h) * kDH;
#pragma unroll 2
      for (int idx = lane; idx < kNQ * 4; idx += 64) {
        const int q = idx >> 2, c = idx & 3;
        uint4 v4 = *(const uint4*)(Pw + q * kDH + c * 8);
        *(uint4*)(pdst + (size_t)q * kH * kDH + c * 8) = v4;
      }
    }

    if (tt + 1 < hi) __syncthreads();              // B3: before next staging
  }
}

// ---------------------------------------------------------------------------
// Combine: block [0,480) = (b,q) partial-sum + epilogue; block 480 = wd total
// ---------------------------------------------------------------------------
__global__ __launch_bounds__(256) void combine_kernel(
    const float* __restrict__ Pl, const unsigned short* __restrict__ Po,
    const int* __restrict__ numv,
    const float* __restrict__ Wo, const float* __restrict__ bo,
    const float* __restrict__ wdp,
    float* __restrict__ out)
{
  const int bq = blockIdx.x;
  const int tid = threadIdx.x;

  if (bq == kB * kNQ) {     // wd finalize over 384 partials
    float v = wdp[tid] + ((tid < 128) ? wdp[tid + 256] : 0.0f);
#pragma unroll
    for (int off = 32; off > 0; off >>= 1) v += __shfl_down(v, off);
    __shared__ float red[4];
    if ((tid & 63) == 0) red[tid >> 6] = v;
    __syncthreads();
    if (tid == 0)
      out[(size_t)kB * kNQ * kC] = red[0] + red[1] + red[2] + red[3];
    return;
  }

  const int b = bq / kNQ, q = bq % kNQ;
  const int h = tid >> 5, kk = tid & 31;

  // chunk-id range for batch b
  int base = 0, cnt = 0, S = 0;
#pragma unroll
  for (int bb = 0; bb < kB; ++bb) {
    const int c3 = 3 * ((numv[bb + 1] - numv[bb] + kCH - 1) / kCH);
    if (bb == b) { base = S; cnt = c3; }
    S += c3;
  }

  float l = 0.0f, oacc = 0.0f;
#pragma unroll 4
  for (int i = 0; i < cnt; ++i) {
    const size_t idx = ((size_t)(base + i) * kNQ + q) * kH + h;
    l += Pl[idx];
    oacc += bf16_to_f32(Po[idx * kDH + kk]);
  }
  const float attn = oacc / l;

  __shared__ float row[kC];
  row[tid] = attn;
  __syncthreads();

  const float4* wr = (const float4*)(Wo + (size_t)tid * kC);
  const float4* rr = (const float4*)row;
  float s = 0.0f;
#pragma unroll
  for (int j = 0; j < kC / 4; ++j) {
    float4 w = wr[j], v = rr[j];
    s = fmaf(v.x, w.x, s); s = fmaf(v.y, w.y, s);
    s = fmaf(v.z, w.z, s); s = fmaf(v.w, w.w, s);
  }
  s += bo[tid];
  const float y = attn + fmaxf(s, 0.0f);

  float v = y * y;
#pragma unroll
  for (int off = 32; off > 0; off >>= 1) v += __shfl_down(v, off);
  __shared__ float red[4];
  if ((tid & 63) == 0) red[tid >> 6] = v;
  __syncthreads();
  const float tot = red[0] + red[1] + red[2] + red[3];
  const float nrm = fmaxf(sqrtf(tot), 1e-12f);
  out[(size_t)bq * kC + tid] = y / nrm;
}

// ---------------------------------------------------------------------------
extern "C" void kernel_launch(void* const* d_in, const int* in_sizes, int n_in,
                              void* d_out, int out_size, void* d_ws, size_t ws_size,
                              hipStream_t stream) {
  const float* x    = (const float*)d_in[0];
  const float* ox   = (const float*)d_in[1];
  const float* ev   = (const float*)d_in[2];
  // d_in[3] = mask_cross: recomputed from numv, unused
  const int*   numv = (const int*)d_in[4];
  const float* WqG  = (const float*)d_in[5];
  const float* WqD  = (const float*)d_in[6];
  const float* WqL  = (const float*)d_in[7];
  const float* WkG  = (const float*)d_in[8];
  const float* WkD  = (const float*)d_in[9];
  const float* WkL  = (const float*)d_in[10];
  const float* WvG  = (const float*)d_in[11];
  const float* bvG  = (const float*)d_in[12];
  const float* WvD  = (const float*)d_in[13];
  const float* bvD  = (const float*)d_in[14];
  const float* WvL  = (const float*)d_in[15];
  const float* bvL  = (const float*)d_in[16];
  const float* Wo   = (const float*)d_in[17];
  const float* bo   = (const float*)d_in[18];

  float* out = (float*)d_out;
  char*  ws  = (char*)d_ws;

  // workspace layout (bytes)
  size_t off = 0;
  float* Qw = (float*)(ws + off);                   off += 491520;   // 16*30*256*4
  unsigned short* Qb   = (unsigned short*)(ws + off); off += 262144; // 16*32*256*2
  unsigned short* Wb   = (unsigned short*)(ws + off); off += 393216; // 3*256*256*2
  unsigned short* WkT  = (unsigned short*)(ws + off); off += 393216; // 3*256*256*2
  unsigned short* Wqkb = (unsigned short*)(ws + off); off += 6291456;// 384*32*256*2
  float* Pl = (float*)(ws + off);           off += (size_t)kMaxT * kNQ * kH * 4;
  unsigned short* Po = (unsigned short*)(ws + off);
  off += (size_t)kMaxT * kNQ * kH * kDH * 2;
  float* wdp = (float*)(ws + off);          off += 1536;    // 384 partials

  prep_kernel<<<1040, 256, 0, stream>>>(ev, WqG, WqD, WqL,
                                        WkG, WkD, WkL, WvG, WvD, WvL,
                                        Wb, WkT, Qw, Qb, wdp);
  wqk_kernel<<<48, 512, 0, stream>>>(Qb, WkT, Wqkb);
  chunk_kernel<<<kGrid, 512, 0, stream>>>(
      x, ox, numv, Wb, bvG, bvD, bvL, Wqkb, Pl, Po);
  combine_kernel<<<kB * kNQ + 1, 256, 0, stream>>>(Pl, Po, numv, Wo, bo, wdp, out);
}

// Round 11
// 95.756 us; speedup vs baseline: 1.6051x; 1.6051x over previous
//
#include <hip/hip_runtime.h>
#include <math.h>

// ---------------------------------------------------------------------------
// GraphMultisetTransformer forward, MI355X round 11:
//   - CH=64 (R9 memory profile: FETCH ~= live x/ox only, B-operands L2-hit)
//   - Po bf16, [tt][h][q][dh] layout, LDS o-transpose -> fully dense stores
//   - cross-chunk register prefetch + non-draining barriers
//     (s_waitcnt lgkmcnt(0) + raw s_barrier: LDS-only sync, global loads
//      stay in flight across barriers)
//   - grid 256 (1 block/CU, ~2.2 chunks/block so prefetch engages)
// ---------------------------------------------------------------------------

typedef __bf16 bf16x8 __attribute__((ext_vector_type(8)));
typedef float  f32x4  __attribute__((ext_vector_type(4)));

namespace {
constexpr int kB   = 16;
constexpr int kN   = 4096;
constexpr int kC   = 256;
constexpr int kEV  = 64;
constexpr int kH   = 8;
constexpr int kDH  = 32;
constexpr int kNQ  = 30;
constexpr int kCH  = 64;            // chunk rows
constexpr int kMaxT = 1056;         // cap for Pl/Po sizing
constexpr int kGrid = 256;          // chunk grid (1 block/CU)
constexpr float kScale = 0.625f;    // 1/(16*0.1)
}

// LDS-only barrier: DOES NOT drain vmcnt -> prefetch loads stay in flight.
// Safe because B1/B2/B3 only order LDS traffic; pending global loads write
// registers (no cross-wave visibility needed).
#define BAR_LDS() do {                                        \
    asm volatile("s_waitcnt lgkmcnt(0)" ::: "memory");        \
    __builtin_amdgcn_s_barrier();                             \
    __builtin_amdgcn_sched_barrier(0);                        \
  } while (0)

__device__ __forceinline__ unsigned short f32_to_bf16(float f) {
  unsigned int u = __float_as_uint(f);
  unsigned int r = (u + 0x7FFFu + ((u >> 16) & 1u)) >> 16;
  return (unsigned short)r;
}
__device__ __forceinline__ unsigned int pack_bf16(float a, float b) {
  return (unsigned int)f32_to_bf16(a) | ((unsigned int)f32_to_bf16(b) << 16);
}
__device__ __forceinline__ float bf16_to_f32(unsigned short u) {
  return __uint_as_float((unsigned int)u << 16);
}
__device__ __forceinline__ f32x4 splat4(float v) {
  f32x4 r; r[0] = v; r[1] = v; r[2] = v; r[3] = v; return r;
}
// 2-way-free swizzle for [64][256]bf16 tiles read as row-lane A-frags
__device__ __forceinline__ int swz_f(int row) {
  return ((row & 7) << 2) | (((row >> 3) & 1) << 1);
}

// ---------------------------------------------------------------------------
// prep: [0,96) Wv f32->bf16 | [96,144) Wk -> bf16 transposed (WkT) |
//       [144,656) Q proj -> Qw f32 + Qb bf16*scale | [656,1040) wd partials
// ---------------------------------------------------------------------------
__global__ __launch_bounds__(256) void prep_kernel(
    const float* __restrict__ ev,
    const float* __restrict__ WqG, const float* __restrict__ WqD,
    const float* __restrict__ WqL,
    const float* __restrict__ WkG, const float* __restrict__ WkD,
    const float* __restrict__ WkL,
    const float* __restrict__ WvG, const float* __restrict__ WvD,
    const float* __restrict__ WvL,
    unsigned short* __restrict__ Wb,     // 3 x Wv bf16
    unsigned short* __restrict__ WkT,    // 3 x Wk^T bf16
    float* __restrict__ Qw, unsigned short* __restrict__ Qb,
    float* __restrict__ wdp)
{
  const int bid = blockIdx.x, tid = threadIdx.x;

  if (bid < 96) {                       // ---- Wv convert ----
    const int mat = bid >> 5;
    const float* src = (mat == 0) ? WvG : (mat == 1) ? WvD : WvL;
    const int i0 = (((bid & 31) << 8) + tid) * 8;
    const float4* s4 = (const float4*)(src + i0);
    float4 a = s4[0], b = s4[1];
    uint4 pack = make_uint4(pack_bf16(a.x, a.y), pack_bf16(a.z, a.w),
                            pack_bf16(b.x, b.y), pack_bf16(b.z, b.w));
    *(uint4*)(Wb + (size_t)mat * 65536 + i0) = pack;
    return;
  }

  if (bid < 144) {                      // ---- Wk transpose -> bf16 ----
    __shared__ float ts[64][65];
    const int t2 = bid - 96;
    const int mat = t2 >> 4, tile = t2 & 15;
    const int r0 = (tile >> 2) * 64, c0 = (tile & 3) * 64;
    const float* src = (mat == 0) ? WkG : (mat == 1) ? WkD : WkL;
#pragma unroll
    for (int it = 0; it < 16; ++it) {
      const int idx = tid + it * 256;
      const int r = idx >> 6, c = idx & 63;
      ts[r][c] = src[(size_t)(r0 + r) * kC + c0 + c];
    }
    __syncthreads();
#pragma unroll
    for (int it = 0; it < 16; ++it) {
      const int idx = tid + it * 256;
      const int r = idx >> 6, c = idx & 63;
      WkT[(size_t)mat * 65536 + (size_t)(c0 + r) * kC + r0 + c] =
          f32_to_bf16(ts[c][r]);
    }
    return;
  }

  if (bid < 656) {                      // ---- Q projection ----
    __shared__ float e[kEV];
    const int idx = bid - 144;
    const int b = idx >> 5, qq = idx & 31;
    if (qq >= kNQ) { Qb[((size_t)(b * 32 + qq)) * kC + tid] = 0; return; }
    if (tid < kEV) e[tid] = ev[((size_t)(b * kNQ + qq)) * kEV + tid];
    __syncthreads();
    const float* W = (qq < 10) ? WqG : (qq < 20) ? WqD : WqL;
    const float4* wr = (const float4*)(W + (size_t)tid * kEV);
    const float4* er = (const float4*)e;
    float s = 0.0f;
#pragma unroll
    for (int j = 0; j < kEV / 4; ++j) {
      float4 w = wr[j], v = er[j];
      s = fmaf(v.x, w.x, s); s = fmaf(v.y, w.y, s);
      s = fmaf(v.z, w.z, s); s = fmaf(v.w, w.w, s);
    }
    Qw[((size_t)(b * kNQ + qq)) * kC + tid] = s;
    Qb[((size_t)(b * 32 + qq)) * kC + tid] = f32_to_bf16(s * kScale);
    return;
  }

  // ---- wd partials: one block per (b,g,h), inline Q from ev ----
  {
    __shared__ float evs[10][64];
    __shared__ float Qblk[10][33];
    __shared__ float sred[256];
    const int w = bid - 656;            // [0,384)
    const int b = w / 24, r = w % 24, g = r >> 3, h = r & 7;
    const int lo = g * 10;
    const float* Wqg = (g == 0) ? WqG : (g == 1) ? WqD : WqL;
    for (int i = tid; i < 640; i += 256) {
      const int q = i >> 6, e2 = i & 63;
      evs[q][e2] = ev[((size_t)(b * kNQ + lo + q)) * kEV + e2];
    }
    __syncthreads();
    for (int i = tid; i < 320; i += 256) {
      const int q = i >> 5, kk = i & 31;
      const float* wp = Wqg + (size_t)(h * 32 + kk) * kEV;
      float s = 0.0f;
#pragma unroll
      for (int e4 = 0; e4 < 16; ++e4) {
        float4 ev4 = *(const float4*)&evs[q][e4 * 4];
        float4 w4  = *(const float4*)(wp + e4 * 4);
        s = fmaf(ev4.x, w4.x, s); s = fmaf(ev4.y, w4.y, s);
        s = fmaf(ev4.z, w4.z, s); s = fmaf(ev4.w, w4.w, s);
      }
      Qblk[q][kk] = s;
    }
    __syncthreads();
    float v = 0.0f;
    if (tid < 100) {
      const int i = tid / 10, j = tid % 10;
      float corr = 0.0f;
#pragma unroll
      for (int k = 0; k < kDH; ++k) corr = fmaf(Qblk[i][k], Qblk[j][k], corr);
      const float diff = corr - (i == j ? 1.0f : 0.0f);
      v = diff * diff;
    }
    sred[tid] = v;
    __syncthreads();
    for (int s2 = 128; s2 > 0; s2 >>= 1) {
      if (tid < s2) sred[tid] += sred[tid + s2];
      __syncthreads();
    }
    if (tid == 0) wdp[w] = sqrtf(sred[0]) * (1.0f / 16.0f);
  }
}

// ---------------------------------------------------------------------------
// wqk: Wqk[b,g,h][q 32][k 256] = Qb[b][q][h*32..+32] @ WkT_g[k][h*32..+32]
// grid 48 = (b,g), 512 thr (wave = head). 32 MFMA/wave.
// ---------------------------------------------------------------------------
__global__ __launch_bounds__(512) void wqk_kernel(
    const unsigned short* __restrict__ Qb,
    const unsigned short* __restrict__ WkT,
    unsigned short* __restrict__ Wqkb)
{
  const int bid = blockIdx.x, tid = threadIdx.x;
  const int b = bid / 3, g = bid % 3;
  const int lane = tid & 63, h = tid >> 6;
  const int lg = lane >> 4, lr = lane & 15;

  const unsigned short* WkT_g = WkT + (size_t)g * 65536;

  bf16x8 aq[2];
#pragma unroll
  for (int mt = 0; mt < 2; ++mt)
    aq[mt] = *reinterpret_cast<const bf16x8*>(
        Qb + (size_t)(b * 32 + mt * 16 + lr) * kC + h * 32 + lg * 8);

  f32x4 acc[2][16];
#pragma unroll
  for (int mt = 0; mt < 2; ++mt)
#pragma unroll
    for (int nt = 0; nt < 16; ++nt) acc[mt][nt] = splat4(0.0f);

#pragma unroll
  for (int nt = 0; nt < 16; ++nt) {
    bf16x8 bw = *reinterpret_cast<const bf16x8*>(
        WkT_g + (size_t)(nt * 16 + lr) * kC + h * 32 + lg * 8);
    acc[0][nt] = __builtin_amdgcn_mfma_f32_16x16x32_bf16(aq[0], bw, acc[0][nt], 0, 0, 0);
    acc[1][nt] = __builtin_amdgcn_mfma_f32_16x16x32_bf16(aq[1], bw, acc[1][nt], 0, 0, 0);
  }

  unsigned short* dst = Wqkb + ((size_t)((b * 3 + g) * 8 + h)) * 32 * kC;
#pragma unroll
  for (int mt = 0; mt < 2; ++mt)
#pragma unroll
    for (int nt = 0; nt < 16; ++nt)
#pragma unroll
      for (int j = 0; j < 4; ++j) {
        const int q = mt * 16 + lg * 4 + j;
        dst[(size_t)q * kC + nt * 16 + lr] = f32_to_bf16(acc[mt][nt][j]);
      }
}

// ---------------------------------------------------------------------------
// Chunk kernel: grid = 256, 512 thr, 64KB LDS, 1 block/CU, ~2.2 chunks each.
// Per chunk: write prefetched regs -> LDS, B1, issue next-tile loads,
// S-proj/exp/Pl, V-proj, B2, P/Vt -> LDS, PV, o -> LDS transpose,
// dense bf16 Po store, B3.
// ---------------------------------------------------------------------------
__global__ __launch_bounds__(512, 2) void chunk_kernel(
    const float* __restrict__ x, const float* __restrict__ ox,
    const int* __restrict__ numv,
    const unsigned short* __restrict__ Wb,      // 3 Wv matrices bf16
    const float* __restrict__ bvG, const float* __restrict__ bvD,
    const float* __restrict__ bvL,
    const unsigned short* __restrict__ Wqkb,    // [b,g,h][32][256] bf16
    float* __restrict__ Pl, unsigned short* __restrict__ Po)
{
  __shared__ unsigned short Xs[kCH * kC];   // x staging -> P/o (8 x 4KB slots)
  __shared__ unsigned short Ov[kCH * kC];   // ox staging -> Vt

  const int tid = threadIdx.x;
  const int lane = tid & 63, wv = tid >> 6;
  const int lg = lane >> 4, lr = lane & 15;
  const int wcol0 = wv * 32;
  const int h = wv;                                  // wave = head

  int nv[17];
#pragma unroll
  for (int i = 0; i < 17; ++i) nv[i] = numv[i];
  int Tall = 0;
#pragma unroll
  for (int bb = 0; bb < kB; ++bb)
    Tall += 3 * ((nv[bb + 1] - nv[bb] + kCH - 1) / kCH);

  const int vp = (blockIdx.x & 7) * (kGrid / 8) + (blockIdx.x >> 3);
  const int lo = (vp * Tall) / kGrid;
  const int hi = ((vp + 1) * Tall) / kGrid;
  if (lo >= hi) return;

  auto decode = [&](int tt, int& b, int& g, int& ch) {
    int rem = tt; b = -1; g = 0; ch = 0;
#pragma unroll
    for (int bb = 0; bb < kB; ++bb) {
      const int cb = (nv[bb + 1] - nv[bb] + kCH - 1) / kCH;
#pragma unroll
      for (int gg = 0; gg < 3; ++gg) {
        if (b < 0) { if (rem < cb) { b = bb; g = gg; ch = rem; } else rem -= cb; }
      }
    }
  };

  float4 xa[8], oa[8];
  auto issue = [&](int b, int g, int ch) {
    const int d = nv[b + 1] - nv[b];
    const int row0 = g * d + ch * kCH;
    const float* xb = x + (size_t)b * kN * kC;
    const float* ob = ox + (size_t)b * kN * kC;
#pragma unroll
    for (int i = 0; i < 4; ++i) {
      const int cid = tid + i * 512;               // [0,2048) 32B slots
      const int row = cid >> 5, c5 = cid & 31;
      const int rg = min(row0 + row, kN - 1);
      const size_t off = (size_t)rg * kC + c5 * 8;
      const float4* sx = (const float4*)(xb + off);
      xa[2 * i] = sx[0]; xa[2 * i + 1] = sx[1];
      const float4* so = (const float4*)(ob + off);
      oa[2 * i] = so[0]; oa[2 * i + 1] = so[1];
    }
  };

  int pb, pg, pch;                  // tile currently in xa/oa
  decode(lo, pb, pg, pch);
  issue(pb, pg, pch);

  for (int tt = lo; tt < hi; ++tt) {
    const int b = pb, g = pg, ch = pch;
    const int d = nv[b + 1] - nv[b];
    const int row0 = g * d + ch * kCH;
    const int nvalid = min(min(kCH, d - ch * kCH), kN - row0);

    const unsigned short* Wv_g = Wb + (size_t)g * 65536;
    const float* bv = (g == 0) ? bvG : (g == 1) ? bvD : bvL;
    const unsigned short* Wqk_h =
        Wqkb + ((size_t)((b * 3 + g) * 8 + h)) * 32 * kC;

    // ---- write prefetched regs -> swizzled LDS tiles ----
#pragma unroll
    for (int i = 0; i < 4; ++i) {
      const int cid = tid + i * 512;
      const int row = cid >> 5, c5 = cid & 31;
      const int base = row * kC + ((c5 ^ swz_f(row)) * 8);
      *(uint4*)(Xs + base) = make_uint4(
          pack_bf16(xa[2 * i].x, xa[2 * i].y), pack_bf16(xa[2 * i].z, xa[2 * i].w),
          pack_bf16(xa[2 * i + 1].x, xa[2 * i + 1].y),
          pack_bf16(xa[2 * i + 1].z, xa[2 * i + 1].w));
      *(uint4*)(Ov + base) = make_uint4(
          pack_bf16(oa[2 * i].x, oa[2 * i].y), pack_bf16(oa[2 * i].z, oa[2 * i].w),
          pack_bf16(oa[2 * i + 1].x, oa[2 * i + 1].y),
          pack_bf16(oa[2 * i + 1].z, oa[2 * i + 1].w));
    }
    BAR_LDS();                                       // B1: tiles staged

    // ---- prefetch next tile (loads in flight across barriers/compute) ----
    if (tt + 1 < hi) { decode(tt + 1, pb, pg, pch); issue(pb, pg, pch); }

    // ---- S-projection: S[key 64][q 32] = X @ Wqk_h^T ----
    f32x4 s[4][2];
#pragma unroll
    for (int m = 0; m < 4; ++m)
#pragma unroll
      for (int n = 0; n < 2; ++n) s[m][n] = splat4(0.0f);

#pragma unroll
    for (int kt = 0; kt < 8; ++kt) {
      bf16x8 a[4];
#pragma unroll
      for (int m = 0; m < 4; ++m) {
        const int row = m * 16 + lr;
        const int c16 = (kt * 4 + lg) ^ swz_f(row);
        a[m] = *reinterpret_cast<const bf16x8*>(Xs + row * kC + c16 * 8);
      }
      const int k0 = kt * 32 + lg * 8;
#pragma unroll
      for (int n = 0; n < 2; ++n) {
        bf16x8 bq = *reinterpret_cast<const bf16x8*>(
            Wqk_h + (size_t)(n * 16 + lr) * kC + k0);
#pragma unroll
        for (int m = 0; m < 4; ++m)
          s[m][n] = __builtin_amdgcn_mfma_f32_16x16x32_bf16(a[m], bq, s[m][n], 0, 0, 0);
      }
    }

    // ---- exp -> packed bf16 P in regs; row-sums ----
    unsigned int pp[4][2][2];
    f32x4 lsum[2];
    lsum[0] = splat4(0.0f); lsum[1] = splat4(0.0f);
#pragma unroll
    for (int m = 0; m < 4; ++m)
#pragma unroll
      for (int n = 0; n < 2; ++n) {
        f32x4 pv;
#pragma unroll
        for (int j = 0; j < 4; ++j) {
          const int key = m * 16 + lg * 4 + j;
          pv[j] = (key < nvalid) ? __expf(s[m][n][j]) : 0.0f;
        }
        lsum[n] += pv;
        pp[m][n][0] = pack_bf16(pv[0], pv[1]);
        pp[m][n][1] = pack_bf16(pv[2], pv[3]);
      }
    float ls[2];
#pragma unroll
    for (int n = 0; n < 2; ++n) {
      float v = (lsum[n][0] + lsum[n][1]) + (lsum[n][2] + lsum[n][3]);
      v += __shfl_xor(v, 16);
      v += __shfl_xor(v, 32);
      ls[n] = v;
    }
    if (lg == 0) {
#pragma unroll
      for (int n = 0; n < 2; ++n) {
        const int q = n * 16 + lr;
        if (q < kNQ) Pl[((size_t)tt * kNQ + q) * kH + h] = ls[n];
      }
    }

    // ---- V projection (acc in regs across B2) ----
    f32x4 vacc[4][2];
#pragma unroll
    for (int n = 0; n < 2; ++n) {
      const float bvv = bv[wcol0 + n * 16 + lr];
#pragma unroll
      for (int m = 0; m < 4; ++m) vacc[m][n] = splat4(bvv);
    }
#pragma unroll
    for (int kt = 0; kt < 8; ++kt) {
      bf16x8 a[4];
#pragma unroll
      for (int m = 0; m < 4; ++m) {
        const int row = m * 16 + lr;
        const int c16 = (kt * 4 + lg) ^ swz_f(row);
        a[m] = *reinterpret_cast<const bf16x8*>(Ov + row * kC + c16 * 8);
      }
      const int k0 = kt * 32 + lg * 8;
#pragma unroll
      for (int n = 0; n < 2; ++n) {
        bf16x8 bw = *reinterpret_cast<const bf16x8*>(
            Wv_g + (size_t)(wcol0 + n * 16 + lr) * kC + k0);
#pragma unroll
        for (int m = 0; m < 4; ++m)
          vacc[m][n] = __builtin_amdgcn_mfma_f32_16x16x32_bf16(a[m], bw, vacc[m][n], 0, 0, 0);
      }
    }
    BAR_LDS();                     // B2: all Xs/Ov reads done; safe to overwrite

    // ---- P -> own-wave Xs slot [32 q][64 key] (4KB) ----
    unsigned short* Pw = Xs + wv * 2048;
#pragma unroll
    for (int m = 0; m < 4; ++m)
#pragma unroll
      for (int n = 0; n < 2; ++n) {
        const int q = n * 16 + lr;
        const int ckp = (2 * m + (lg >> 1)) ^ (q & 7);
        unsigned short* pa = Pw + q * kCH + ckp * 8 + (lg & 1) * 4;
        *(unsigned int*)(pa) = pp[m][n][0];
        *(unsigned int*)(pa + 2) = pp[m][n][1];
      }

    // ---- Vt -> Ov space: [col][key] swizzled (own cols) ----
#pragma unroll
    for (int m = 0; m < 4; ++m)
#pragma unroll
      for (int n = 0; n < 2; ++n) {
        const int col = wcol0 + n * 16 + lr;
        const int r0 = m * 16 + lg * 4;
        const int ck = (r0 >> 3) ^ (col & 7);
        *(uint2*)(Ov + col * kCH + ck * 8 + (r0 & 7)) =
            make_uint2(pack_bf16(vacc[m][n][0], vacc[m][n][1]),
                       pack_bf16(vacc[m][n][2], vacc[m][n][3]));
      }

    // ---- PV: O[q][dh] = sum_key P[q][key] * V[key][dh]  (same-wave LDS) ----
    f32x4 o[2][2];
#pragma unroll
    for (int m = 0; m < 2; ++m)
#pragma unroll
      for (int n = 0; n < 2; ++n) o[m][n] = splat4(0.0f);

#pragma unroll
    for (int ks = 0; ks < 2; ++ks) {
      bf16x8 ap[2];
#pragma unroll
      for (int mq = 0; mq < 2; ++mq) {
        const int q = mq * 16 + lr;
        ap[mq] = *reinterpret_cast<const bf16x8*>(
            Pw + q * kCH + (((ks * 4 + lg) ^ (q & 7))) * 8);
      }
#pragma unroll
      for (int n = 0; n < 2; ++n) {
        const int col = wcol0 + n * 16 + lr;
        bf16x8 bvf = *reinterpret_cast<const bf16x8*>(
            Ov + col * kCH + (((ks * 4 + lg) ^ (col & 7))) * 8);
        o[0][n] = __builtin_amdgcn_mfma_f32_16x16x32_bf16(ap[0], bvf, o[0][n], 0, 0, 0);
        o[1][n] = __builtin_amdgcn_mfma_f32_16x16x32_bf16(ap[1], bvf, o[1][n], 0, 0, 0);
      }
    }

    // ---- o -> Pw (dead P slot) as [32 q][32 dh] bf16, then dense stores ----
#pragma unroll
    for (int mq = 0; mq < 2; ++mq)
#pragma unroll
      for (int n = 0; n < 2; ++n)
#pragma unroll
        for (int j = 0; j < 4; ++j) {
          const int q = mq * 16 + lg * 4 + j;
          Pw[q * kDH + n * 16 + lr] = f32_to_bf16(o[mq][n][j]);
        }
    // wave-private copy: lane i moves bytes [16i,16i+16) -> fully dense
    {
      unsigned short* pdst = Po + ((size_t)tt * kH + h) * (kNQ * kDH);
      if (lane < 120) {
        uint4 v4 = *(const uint4*)(Pw + lane * 8);
        *(uint4*)(pdst + lane * 8) = v4;
      }
    }

    if (tt + 1 < hi) BAR_LDS();              // B3: before next tile's LDS write
  }
}

// ---------------------------------------------------------------------------
// Combine: block [0,480) = (b,q) partial-sum + epilogue; block 480 = wd total
// ---------------------------------------------------------------------------
__global__ __launch_bounds__(256) void combine_kernel(
    const float* __restrict__ Pl, const unsigned short* __restrict__ Po,
    const int* __restrict__ numv,
    const float* __restrict__ Wo, const float* __restrict__ bo,
    const float* __restrict__ wdp,
    float* __restrict__ out)
{
  const int bq = blockIdx.x;
  const int tid = threadIdx.x;

  if (bq == kB * kNQ) {     // wd finalize over 384 partials
    float v = wdp[tid] + ((tid < 128) ? wdp[tid + 256] : 0.0f);
#pragma unroll
    for (int off = 32; off > 0; off >>= 1) v += __shfl_down(v, off);
    __shared__ float red[4];
    if ((tid & 63) == 0) red[tid >> 6] = v;
    __syncthreads();
    if (tid == 0)
      out[(size_t)kB * kNQ * kC] = red[0] + red[1] + red[2] + red[3];
    return;
  }

  const int b = bq / kNQ, q = bq % kNQ;
  const int h = tid >> 5, kk = tid & 31;

  // chunk-id range for batch b
  int base = 0, cnt = 0, S = 0;
#pragma unroll
  for (int bb = 0; bb < kB; ++bb) {
    const int c3 = 3 * ((numv[bb + 1] - numv[bb] + kCH - 1) / kCH);
    if (bb == b) { base = S; cnt = c3; }
    S += c3;
  }

  float l = 0.0f, oacc = 0.0f;
#pragma unroll 4
  for (int i = 0; i < cnt; ++i) {
    const int t = base + i;
    l += Pl[((size_t)t * kNQ + q) * kH + h];
    oacc += bf16_to_f32(Po[((size_t)t * kH + h) * (kNQ * kDH) + q * kDH + kk]);
  }
  const float attn = oacc / l;

  __shared__ float row[kC];
  row[tid] = attn;
  __syncthreads();

  const float4* wr = (const float4*)(Wo + (size_t)tid * kC);
  const float4* rr = (const float4*)row;
  float s = 0.0f;
#pragma unroll
  for (int j = 0; j < kC / 4; ++j) {
    float4 w = wr[j], v = rr[j];
    s = fmaf(v.x, w.x, s); s = fmaf(v.y, w.y, s);
    s = fmaf(v.z, w.z, s); s = fmaf(v.w, w.w, s);
  }
  s += bo[tid];
  const float y = attn + fmaxf(s, 0.0f);

  float v = y * y;
#pragma unroll
  for (int off = 32; off > 0; off >>= 1) v += __shfl_down(v, off);
  __shared__ float red[4];
  if ((tid & 63) == 0) red[tid >> 6] = v;
  __syncthreads();
  const float tot = red[0] + red[1] + red[2] + red[3];
  const float nrm = fmaxf(sqrtf(tot), 1e-12f);
  out[(size_t)bq * kC + tid] = y / nrm;
}

// ---------------------------------------------------------------------------
extern "C" void kernel_launch(void* const* d_in, const int* in_sizes, int n_in,
                              void* d_out, int out_size, void* d_ws, size_t ws_size,
                              hipStream_t stream) {
  const float* x    = (const float*)d_in[0];
  const float* ox   = (const float*)d_in[1];
  const float* ev   = (const float*)d_in[2];
  // d_in[3] = mask_cross: recomputed from numv, unused
  const int*   numv = (const int*)d_in[4];
  const float* WqG  = (const float*)d_in[5];
  const float* WqD  = (const float*)d_in[6];
  const float* WqL  = (const float*)d_in[7];
  const float* WkG  = (const float*)d_in[8];
  const float* WkD  = (const float*)d_in[9];
  const float* WkL  = (const float*)d_in[10];
  const float* WvG  = (const float*)d_in[11];
  const float* bvG  = (const float*)d_in[12];
  const float* WvD  = (const float*)d_in[13];
  const float* bvD  = (const float*)d_in[14];
  const float* WvL  = (const float*)d_in[15];
  const float* bvL  = (const float*)d_in[16];
  const float* Wo   = (const float*)d_in[17];
  const float* bo   = (const float*)d_in[18];

  float* out = (float*)d_out;
  char*  ws  = (char*)d_ws;

  // workspace layout (bytes)
  size_t off = 0;
  float* Qw = (float*)(ws + off);                   off += 491520;   // 16*30*256*4
  unsigned short* Qb   = (unsigned short*)(ws + off); off += 262144; // 16*32*256*2
  unsigned short* Wb   = (unsigned short*)(ws + off); off += 393216; // 3*256*256*2
  unsigned short* WkT  = (unsigned short*)(ws + off); off += 393216; // 3*256*256*2
  unsigned short* Wqkb = (unsigned short*)(ws + off); off += 6291456;// 384*32*256*2
  float* Pl = (float*)(ws + off);           off += (size_t)kMaxT * kNQ * kH * 4;
  unsigned short* Po = (unsigned short*)(ws + off);
  off += (size_t)kMaxT * kH * kNQ * kDH * 2;
  float* wdp = (float*)(ws + off);          off += 1536;    // 384 partials

  prep_kernel<<<1040, 256, 0, stream>>>(ev, WqG, WqD, WqL,
                                        WkG, WkD, WkL, WvG, WvD, WvL,
                                        Wb, WkT, Qw, Qb, wdp);
  wqk_kernel<<<48, 512, 0, stream>>>(Qb, WkT, Wqkb);
  chunk_kernel<<<kGrid, 512, 0, stream>>>(
      x, ox, numv, Wb, bvG, bvD, bvL, Wqkb, Pl, Po);
  combine_kernel<<<kB * kNQ + 1, 256, 0, stream>>>(Pl, Po, numv, Wo, bo, wdp, out);
}